// Round 1
// baseline (638.977 us; speedup 1.0000x reference)
//
#include <hip/hip_runtime.h>
#include <math.h>

#define NN 50000
#define NE 800000
#define NG 50
#define F0 128
#define F1 64
#define F2 32

__device__ __forceinline__ float lrelu(float v, float slope) {
    return v > 0.0f ? v : v * slope;
}

// float atomic max via int/uint trick (init must be -inf)
__device__ __forceinline__ void atomicMaxF(float* addr, float val) {
    if (val >= 0.0f) atomicMax((int*)addr, __float_as_int(val));
    else atomicMin((unsigned int*)addr, (unsigned int)__float_as_int(val));
}

// ---- GEMM1: z = x@W (NN x 128 @ 128 x 64); el = z@al, er = z@ar fused
__global__ __launch_bounds__(256) void gemm1_kernel(
    const float* __restrict__ x, const float* __restrict__ W,
    const float* __restrict__ al, const float* __restrict__ ar,
    float* __restrict__ z, float* __restrict__ el, float* __restrict__ er)
{
    __shared__ float Ws[F0 * F1];
    __shared__ float xs[4][F0];
    int tid = threadIdx.x;
    for (int i = tid; i < F0 * F1; i += 256) Ws[i] = W[i];
    __syncthreads();
    int wave = tid >> 6, lane = tid & 63;
    float a_l = al[lane], a_r = ar[lane];
    for (int row = blockIdx.x * 4 + wave; row < NN; row += gridDim.x * 4) {
        float2 xv = *reinterpret_cast<const float2*>(&x[row * F0 + lane * 2]);
        xs[wave][lane * 2]     = xv.x;
        xs[wave][lane * 2 + 1] = xv.y;
        float acc = 0.f;
        #pragma unroll 16
        for (int k = 0; k < F0; ++k)
            acc = fmaf(xs[wave][k], Ws[k * F1 + lane], acc);
        z[row * F1 + lane] = acc;
        float pl = acc * a_l, pr = acc * a_r;
        #pragma unroll
        for (int mm = 1; mm < 64; mm <<= 1) {
            pl += __shfl_xor(pl, mm);
            pr += __shfl_xor(pr, mm);
        }
        if (lane == 0) { el[row] = pl; er[row] = pr; }
    }
}

// ---- GEMM2: z = h@W (NN x 64 @ 64 x 32); half-wave per row
__global__ __launch_bounds__(256) void gemm2_kernel(
    const float* __restrict__ h, const float* __restrict__ W,
    const float* __restrict__ al, const float* __restrict__ ar,
    float* __restrict__ z, float* __restrict__ el, float* __restrict__ er)
{
    __shared__ float Ws[F1 * F2];
    __shared__ float xs[4][2 * F1];
    int tid = threadIdx.x;
    for (int i = tid; i < F1 * F2; i += 256) Ws[i] = W[i];
    __syncthreads();
    int wave = tid >> 6, lane = tid & 63;
    int half = lane >> 5, j = lane & 31;
    float a_l = al[j], a_r = ar[j];
    for (int r0 = (blockIdx.x * 4 + wave) * 2; r0 < NN; r0 += gridDim.x * 8) {
        // stage two consecutive rows (128 contiguous floats)
        float2 xv = *reinterpret_cast<const float2*>(&h[(size_t)r0 * F1 + lane * 2]);
        xs[wave][lane * 2]     = xv.x;
        xs[wave][lane * 2 + 1] = xv.y;
        int row = r0 + half;
        float acc = 0.f;
        #pragma unroll 16
        for (int k = 0; k < F1; ++k)
            acc = fmaf(xs[wave][half * F1 + k], Ws[k * F2 + j], acc);
        z[row * F2 + j] = acc;
        float pl = acc * a_l, pr = acc * a_r;
        #pragma unroll
        for (int mm = 1; mm < 32; mm <<= 1) {
            pl += __shfl_xor(pl, mm);
            pr += __shfl_xor(pr, mm);
        }
        if (j == 0) { el[row] = pl; er[row] = pr; }
    }
}

// ---- init m=-inf, s=0, agg=0
__global__ void prep_kernel(float* __restrict__ m, float* __restrict__ s,
                            float* __restrict__ agg, int aggn)
{
    int stride = gridDim.x * blockDim.x;
    int t0 = blockIdx.x * blockDim.x + threadIdx.x;
    for (int i = t0; i < NN; i += stride) { m[i] = -INFINITY; s[i] = 0.f; }
    for (int i = t0; i < aggn; i += stride) agg[i] = 0.f;
}

// ---- e = lrelu(el[src]+er[dst], 0.2); segment max into m[dst]
__global__ void edge_max_kernel(const int* __restrict__ src, const int* __restrict__ dst,
    const float* __restrict__ el, const float* __restrict__ er,
    float* __restrict__ ebuf, float* __restrict__ m)
{
    int e = blockIdx.x * blockDim.x + threadIdx.x;
    if (e >= NE) return;
    int sn = src[e], dn = dst[e];
    float v = lrelu(el[sn] + er[dn], 0.2f);
    ebuf[e] = v;
    atomicMaxF(&m[dn], v);
}

// ---- p = exp(e - m[dst]); segment sum into s[dst]
__global__ void edge_exp_kernel(const int* __restrict__ dst,
    float* __restrict__ ebuf, const float* __restrict__ m, float* __restrict__ s)
{
    int e = blockIdx.x * blockDim.x + threadIdx.x;
    if (e >= NE) return;
    int dn = dst[e];
    float p = expf(ebuf[e] - m[dn]);
    ebuf[e] = p;
    atomicAdd(&s[dn], p);
}

// ---- agg[dst] += (p/s[dst]) * z[src]; one thread per (edge, feature)
template<int F>
__global__ void scatter_kernel(const int* __restrict__ src, const int* __restrict__ dst,
    const float* __restrict__ ebuf, const float* __restrict__ s,
    const float* __restrict__ z, float* __restrict__ agg)
{
    long long tid = (long long)blockIdx.x * blockDim.x + threadIdx.x;
    if (tid >= (long long)NE * F) return;
    int e = (int)(tid / F), f = (int)(tid % F);
    int sn = src[e], dn = dst[e];
    float alpha = ebuf[e] / s[dn];
    atomicAdd(&agg[(size_t)dn * F + f], alpha * z[(size_t)sn * F + f]);
}

// ---- h = lrelu(agg + b, 0.01) in place
template<int F>
__global__ void bias_act_kernel(float* __restrict__ agg, const float* __restrict__ b)
{
    int i = blockIdx.x * blockDim.x + threadIdx.x;
    if (i >= NN * F) return;
    float v = agg[i] + b[i % F];
    agg[i] = lrelu(v, 0.01f);
}

// ---- per-graph mean pool (graph_id sorted); one block per graph
__global__ __launch_bounds__(256) void pool_kernel(
    const float* __restrict__ h2, const int* __restrict__ gid, float* __restrict__ out)
{
    int g = blockIdx.x;
    // lower_bound(g)
    int lo = 0, hi = NN;
    while (lo < hi) { int mid = (lo + hi) >> 1; if (gid[mid] < g) lo = mid + 1; else hi = mid; }
    int start = lo;
    hi = NN;
    while (lo < hi) { int mid = (lo + hi) >> 1; if (gid[mid] < g + 1) lo = mid + 1; else hi = mid; }
    int end = lo;

    int f = threadIdx.x & 31, r = threadIdx.x >> 5; // 8 row-stripes x 32 feats
    float acc = 0.f;
    for (int n = start + r; n < end; n += 8) acc += h2[(size_t)n * F2 + f];
    __shared__ float red[256];
    red[threadIdx.x] = acc;
    __syncthreads();
    for (int st = 128; st >= 32; st >>= 1) {
        if (threadIdx.x < st) red[threadIdx.x] += red[threadIdx.x + st];
        __syncthreads();
    }
    if (threadIdx.x < 32) {
        float cnt = (float)(end - start);
        out[g * F2 + threadIdx.x] = red[threadIdx.x] / fmaxf(cnt, 1.0f);
    }
}

extern "C" void kernel_launch(void* const* d_in, const int* in_sizes, int n_in,
                              void* d_out, int out_size, void* d_ws, size_t ws_size,
                              hipStream_t stream)
{
    const float* x   = (const float*)d_in[0];
    const int*   src = (const int*)d_in[1];
    const int*   dst = (const int*)d_in[2];
    const int*   gid = (const int*)d_in[3];
    const float* W1  = (const float*)d_in[4];
    const float* al1 = (const float*)d_in[5];
    const float* ar1 = (const float*)d_in[6];
    const float* b1  = (const float*)d_in[7];
    const float* W2  = (const float*)d_in[8];
    const float* al2 = (const float*)d_in[9];
    const float* ar2 = (const float*)d_in[10];
    const float* b2  = (const float*)d_in[11];
    float* out = (float*)d_out;

    float* ws   = (float*)d_ws;
    float* z1   = ws;                          // NN*64
    float* agg1 = z1 + (size_t)NN * F1;        // NN*64 (becomes h1)
    float* z2   = agg1 + (size_t)NN * F1;      // NN*32
    float* agg2 = z2 + (size_t)NN * F2;        // NN*32 (becomes h2)
    float* el   = agg2 + (size_t)NN * F2;      // NN
    float* er   = el + NN;                     // NN
    float* m    = er + NN;                     // NN
    float* s    = m + NN;                      // NN
    float* ebuf = s + NN;                      // NE

    // ---- layer 1
    gemm1_kernel<<<1024, 256, 0, stream>>>(x, W1, al1, ar1, z1, el, er);
    prep_kernel<<<2048, 256, 0, stream>>>(m, s, agg1, NN * F1);
    edge_max_kernel<<<(NE + 255) / 256, 256, 0, stream>>>(src, dst, el, er, ebuf, m);
    edge_exp_kernel<<<(NE + 255) / 256, 256, 0, stream>>>(dst, ebuf, m, s);
    scatter_kernel<F1><<<(int)(((long long)NE * F1 + 255) / 256), 256, 0, stream>>>(src, dst, ebuf, s, z1, agg1);
    bias_act_kernel<F1><<<(NN * F1 + 255) / 256, 256, 0, stream>>>(agg1, b1);

    // ---- layer 2
    gemm2_kernel<<<1024, 256, 0, stream>>>(agg1, W2, al2, ar2, z2, el, er);
    prep_kernel<<<2048, 256, 0, stream>>>(m, s, agg2, NN * F2);
    edge_max_kernel<<<(NE + 255) / 256, 256, 0, stream>>>(src, dst, el, er, ebuf, m);
    edge_exp_kernel<<<(NE + 255) / 256, 256, 0, stream>>>(dst, ebuf, m, s);
    scatter_kernel<F2><<<(int)(((long long)NE * F2 + 255) / 256), 256, 0, stream>>>(src, dst, ebuf, s, z2, agg2);
    bias_act_kernel<F2><<<(NN * F2 + 255) / 256, 256, 0, stream>>>(agg2, b2);

    // ---- per-graph mean pool
    pool_kernel<<<NG, 256, 0, stream>>>(agg2, gid, out);
}

// Round 3
// 415.431 us; speedup vs baseline: 1.5381x; 1.5381x over previous
//
#include <hip/hip_runtime.h>
#include <math.h>

#define NN 50000
#define NE 800000
#define NG 50
#define F0 128
#define F1 64
#define F2 32
#define NB 196   // ceil(NN/256)

__device__ __forceinline__ float lrelu(float v, float slope) {
    return v > 0.0f ? v : v * slope;
}

// ---- GEMM1: z = x@W (NN x 128 @ 128 x 64); el = z@al, er = z@ar fused
__global__ __launch_bounds__(256) void gemm1_kernel(
    const float* __restrict__ x, const float* __restrict__ W,
    const float* __restrict__ al, const float* __restrict__ ar,
    float* __restrict__ z, float* __restrict__ el, float* __restrict__ er)
{
    __shared__ float Ws[F0 * F1];
    __shared__ float xs[4][F0];
    int tid = threadIdx.x;
    for (int i = tid; i < F0 * F1; i += 256) Ws[i] = W[i];
    __syncthreads();
    int wave = tid >> 6, lane = tid & 63;
    float a_l = al[lane], a_r = ar[lane];
    for (int row = blockIdx.x * 4 + wave; row < NN; row += gridDim.x * 4) {
        float2 xv = *reinterpret_cast<const float2*>(&x[row * F0 + lane * 2]);
        xs[wave][lane * 2]     = xv.x;
        xs[wave][lane * 2 + 1] = xv.y;
        float acc = 0.f;
        #pragma unroll 16
        for (int k = 0; k < F0; ++k)
            acc = fmaf(xs[wave][k], Ws[k * F1 + lane], acc);
        z[row * F1 + lane] = acc;
        float pl = acc * a_l, pr = acc * a_r;
        #pragma unroll
        for (int mm = 1; mm < 64; mm <<= 1) {
            pl += __shfl_xor(pl, mm);
            pr += __shfl_xor(pr, mm);
        }
        if (lane == 0) { el[row] = pl; er[row] = pr; }
    }
}

// ---- GEMM2: z = h@W (NN x 64 @ 64 x 32); half-wave per row
__global__ __launch_bounds__(256) void gemm2_kernel(
    const float* __restrict__ h, const float* __restrict__ W,
    const float* __restrict__ al, const float* __restrict__ ar,
    float* __restrict__ z, float* __restrict__ el, float* __restrict__ er)
{
    __shared__ float Ws[F1 * F2];
    __shared__ float xs[4][2 * F1];
    int tid = threadIdx.x;
    for (int i = tid; i < F1 * F2; i += 256) Ws[i] = W[i];
    __syncthreads();
    int wave = tid >> 6, lane = tid & 63;
    int half = lane >> 5, j = lane & 31;
    float a_l = al[j], a_r = ar[j];
    for (int r0 = (blockIdx.x * 4 + wave) * 2; r0 < NN; r0 += gridDim.x * 8) {
        float2 xv = *reinterpret_cast<const float2*>(&h[(size_t)r0 * F1 + lane * 2]);
        xs[wave][lane * 2]     = xv.x;
        xs[wave][lane * 2 + 1] = xv.y;
        int row = r0 + half;
        float acc = 0.f;
        #pragma unroll 16
        for (int k = 0; k < F1; ++k)
            acc = fmaf(xs[wave][half * F1 + k], Ws[k * F2 + j], acc);
        z[row * F2 + j] = acc;
        float pl = acc * a_l, pr = acc * a_r;
        #pragma unroll
        for (int mm = 1; mm < 32; mm <<= 1) {
            pl += __shfl_xor(pl, mm);
            pr += __shfl_xor(pr, mm);
        }
        if (j == 0) { el[row] = pl; er[row] = pr; }
    }
}

// ==================== CSR build (once per call, shared by both layers) =====

__global__ void zero_deg_kernel(int* __restrict__ deg)
{
    int i = blockIdx.x * blockDim.x + threadIdx.x;
    if (i < NN) deg[i] = 0;
}

__global__ void count_deg_kernel(const int* __restrict__ dst, int* __restrict__ deg)
{
    int e = blockIdx.x * blockDim.x + threadIdx.x;
    if (e < NE) atomicAdd(&deg[dst[e]], 1);
}

// block-level inclusive scan of deg -> scn, block totals -> bsum
__global__ __launch_bounds__(256) void scan1_kernel(
    const int* __restrict__ deg, int* __restrict__ scn, int* __restrict__ bsum)
{
    __shared__ int tmp[256];
    int i = blockIdx.x * 256 + threadIdx.x;
    int v = (i < NN) ? deg[i] : 0;
    tmp[threadIdx.x] = v;
    __syncthreads();
    for (int off = 1; off < 256; off <<= 1) {
        int t = (threadIdx.x >= off) ? tmp[threadIdx.x - off] : 0;
        __syncthreads();
        tmp[threadIdx.x] += t;
        __syncthreads();
    }
    if (i < NN) scn[i] = tmp[threadIdx.x];
    if (threadIdx.x == 255) bsum[blockIdx.x] = tmp[255];
}

// single block: exclusive scan of NB block sums in place
__global__ __launch_bounds__(256) void scan2_kernel(int* __restrict__ bsum)
{
    __shared__ int tmp[256];
    int v = (threadIdx.x < NB) ? bsum[threadIdx.x] : 0;
    tmp[threadIdx.x] = v;
    __syncthreads();
    for (int off = 1; off < 256; off <<= 1) {
        int t = (threadIdx.x >= off) ? tmp[threadIdx.x - off] : 0;
        __syncthreads();
        tmp[threadIdx.x] += t;
        __syncthreads();
    }
    if (threadIdx.x < NB) bsum[threadIdx.x] = tmp[threadIdx.x] - v; // exclusive
}

// row_start[i] = exclusive scan; fill_pos aliases scn (read own index then overwrite)
__global__ void scan3_kernel(const int* __restrict__ deg, int* __restrict__ scn_fillpos,
                             const int* __restrict__ bsum, int* __restrict__ row_start)
{
    int i = blockIdx.x * 256 + threadIdx.x;
    if (i < NN) {
        int ex = scn_fillpos[i] - deg[i] + bsum[blockIdx.x];
        row_start[i] = ex;
        scn_fillpos[i] = ex;
    }
    if (i == 0) row_start[NN] = NE;
}

__global__ void fill_kernel(const int* __restrict__ src, const int* __restrict__ dst,
                            int* __restrict__ fill_pos, int* __restrict__ srcs)
{
    int e = blockIdx.x * blockDim.x + threadIdx.x;
    if (e >= NE) return;
    int p = atomicAdd(&fill_pos[dst[e]], 1);
    srcs[p] = src[e];
}

// ==================== fused attention aggregation (gather, no atomics) =====
// F=64: one wave per dst node; F=32: half-wave per dst node.
template<int F>
__global__ __launch_bounds__(256) void gat_agg_kernel(
    const int* __restrict__ row_start, const int* __restrict__ srcs,
    const float* __restrict__ el, const float* __restrict__ er,
    const float* __restrict__ z, const float* __restrict__ b,
    float* __restrict__ out, float slope_out)
{
    int tid = blockIdx.x * 256 + threadIdx.x;
    int node0 = tid / F;
    int lane = threadIdx.x & (F - 1);
    int groups_total = (gridDim.x * 256) / F;
    float bb = b[lane];
    for (int node = node0; node < NN; node += groups_total) {
        int beg = row_start[node], end = row_start[node + 1];
        float erd = er[node];
        // pass 1a: segment max
        float lm = -INFINITY;
        for (int i = beg + lane; i < end; i += F)
            lm = fmaxf(lm, lrelu(el[srcs[i]] + erd, 0.2f));
        #pragma unroll
        for (int mm = 1; mm < F; mm <<= 1) lm = fmaxf(lm, __shfl_xor(lm, mm));
        // pass 1b: segment sum of exp
        float ls = 0.f;
        for (int i = beg + lane; i < end; i += F)
            ls += __expf(lrelu(el[srcs[i]] + erd, 0.2f) - lm);
        #pragma unroll
        for (int mm = 1; mm < F; mm <<= 1) ls += __shfl_xor(ls, mm);
        float inv_s = (ls > 0.f) ? 1.0f / ls : 0.f;
        // pass 2: weighted feature gather, lane = feature
        float acc = 0.f;
        for (int i = beg; i < end; ++i) {
            int sn = srcs[i];
            float alpha = __expf(lrelu(el[sn] + erd, 0.2f) - lm) * inv_s;
            acc = fmaf(alpha, z[(size_t)sn * F + lane], acc);
        }
        out[(size_t)node * F + lane] = lrelu(acc + bb, slope_out);
    }
}

// ---- per-graph mean pool (graph_id sorted); one block per graph
__global__ __launch_bounds__(256) void pool_kernel(
    const float* __restrict__ h2, const int* __restrict__ gid, float* __restrict__ out)
{
    int g = blockIdx.x;
    int lo = 0, hi = NN;
    while (lo < hi) { int mid = (lo + hi) >> 1; if (gid[mid] < g) lo = mid + 1; else hi = mid; }
    int start = lo;
    hi = NN;
    while (lo < hi) { int mid = (lo + hi) >> 1; if (gid[mid] < g + 1) lo = mid + 1; else hi = mid; }
    int end = lo;

    int f = threadIdx.x & 31, r = threadIdx.x >> 5;
    float acc = 0.f;
    for (int n = start + r; n < end; n += 8) acc += h2[(size_t)n * F2 + f];
    __shared__ float red[256];
    red[threadIdx.x] = acc;
    __syncthreads();
    for (int st = 128; st >= 32; st >>= 1) {
        if (threadIdx.x < st) red[threadIdx.x] += red[threadIdx.x + st];
        __syncthreads();
    }
    if (threadIdx.x < 32) {
        float cnt = (float)(end - start);
        out[g * F2 + threadIdx.x] = red[threadIdx.x] / fmaxf(cnt, 1.0f);
    }
}

extern "C" void kernel_launch(void* const* d_in, const int* in_sizes, int n_in,
                              void* d_out, int out_size, void* d_ws, size_t ws_size,
                              hipStream_t stream)
{
    const float* x   = (const float*)d_in[0];
    const int*   src = (const int*)d_in[1];
    const int*   dst = (const int*)d_in[2];
    const int*   gid = (const int*)d_in[3];
    const float* W1  = (const float*)d_in[4];
    const float* al1 = (const float*)d_in[5];
    const float* ar1 = (const float*)d_in[6];
    const float* b1  = (const float*)d_in[7];
    const float* W2  = (const float*)d_in[8];
    const float* al2 = (const float*)d_in[9];
    const float* ar2 = (const float*)d_in[10];
    const float* b2  = (const float*)d_in[11];
    float* out = (float*)d_out;

    float* ws   = (float*)d_ws;
    float* z1   = ws;                            // NN*64
    float* h1   = z1 + (size_t)NN * F1;          // NN*64
    float* z2   = h1 + (size_t)NN * F1;          // NN*32
    float* h2   = z2 + (size_t)NN * F2;          // NN*32
    float* el   = h2 + (size_t)NN * F2;          // NN
    float* er   = el + NN;                       // NN
    int* deg       = (int*)(er + NN);            // NN
    int* scn_fill  = deg + NN;                   // NN (scan buf, then fill_pos)
    int* bsum      = scn_fill + NN;              // 256
    int* row_start = bsum + 256;                 // NN+1
    int* srcs      = row_start + NN + 1;         // NE

    // ---- CSR build (dst-sorted adjacency), shared by both layers
    zero_deg_kernel<<<NB, 256, 0, stream>>>(deg);
    count_deg_kernel<<<(NE + 255) / 256, 256, 0, stream>>>(dst, deg);
    scan1_kernel<<<NB, 256, 0, stream>>>(deg, scn_fill, bsum);
    scan2_kernel<<<1, 256, 0, stream>>>(bsum);
    scan3_kernel<<<NB, 256, 0, stream>>>(deg, scn_fill, bsum, row_start);
    fill_kernel<<<(NE + 255) / 256, 256, 0, stream>>>(src, dst, scn_fill, srcs);

    // ---- layer 1
    gemm1_kernel<<<1024, 256, 0, stream>>>(x, W1, al1, ar1, z1, el, er);
    gat_agg_kernel<F1><<<(NN * F1 + 255) / 256, 256, 0, stream>>>(
        row_start, srcs, el, er, z1, b1, h1, 0.01f);

    // ---- layer 2
    gemm2_kernel<<<1024, 256, 0, stream>>>(h1, W2, al2, ar2, z2, el, er);
    gat_agg_kernel<F2><<<(NN * F2 + 255) / 256, 256, 0, stream>>>(
        row_start, srcs, el, er, z2, b2, h2, 0.01f);

    // ---- per-graph mean pool
    pool_kernel<<<NG, 256, 0, stream>>>(h2, gid, out);
}

// Round 4
// 350.161 us; speedup vs baseline: 1.8248x; 1.1864x over previous
//
#include <hip/hip_runtime.h>
#include <math.h>

#define NN 50000
#define NE 800000
#define NG 50
#define F0 128
#define F1 64
#define F2 32
#define NB 196   // ceil(NN/256)

__device__ __forceinline__ float lrelu(float v, float slope) {
    return v > 0.0f ? v : v * slope;
}

// ---- GEMM1: z = x@W (NN x 128 @ 128 x 64); el = z@al, er = z@ar fused
__global__ __launch_bounds__(256) void gemm1_kernel(
    const float* __restrict__ x, const float* __restrict__ W,
    const float* __restrict__ al, const float* __restrict__ ar,
    float* __restrict__ z, float* __restrict__ el, float* __restrict__ er)
{
    __shared__ float Ws[F0 * F1];
    __shared__ float xs[4][F0];
    int tid = threadIdx.x;
    for (int i = tid; i < F0 * F1; i += 256) Ws[i] = W[i];
    __syncthreads();
    int wave = tid >> 6, lane = tid & 63;
    float a_l = al[lane], a_r = ar[lane];
    for (int row = blockIdx.x * 4 + wave; row < NN; row += gridDim.x * 4) {
        float2 xv = *reinterpret_cast<const float2*>(&x[row * F0 + lane * 2]);
        xs[wave][lane * 2]     = xv.x;
        xs[wave][lane * 2 + 1] = xv.y;
        float acc = 0.f;
        #pragma unroll 16
        for (int k = 0; k < F0; ++k)
            acc = fmaf(xs[wave][k], Ws[k * F1 + lane], acc);
        z[row * F1 + lane] = acc;
        float pl = acc * a_l, pr = acc * a_r;
        #pragma unroll
        for (int mm = 1; mm < 64; mm <<= 1) {
            pl += __shfl_xor(pl, mm);
            pr += __shfl_xor(pr, mm);
        }
        if (lane == 0) { el[row] = pl; er[row] = pr; }
    }
}

// ---- GEMM2: z = h@W (NN x 64 @ 64 x 32); half-wave per row
__global__ __launch_bounds__(256) void gemm2_kernel(
    const float* __restrict__ h, const float* __restrict__ W,
    const float* __restrict__ al, const float* __restrict__ ar,
    float* __restrict__ z, float* __restrict__ el, float* __restrict__ er)
{
    __shared__ float Ws[F1 * F2];
    __shared__ float xs[4][2 * F1];
    int tid = threadIdx.x;
    for (int i = tid; i < F1 * F2; i += 256) Ws[i] = W[i];
    __syncthreads();
    int wave = tid >> 6, lane = tid & 63;
    int half = lane >> 5, j = lane & 31;
    float a_l = al[j], a_r = ar[j];
    for (int r0 = (blockIdx.x * 4 + wave) * 2; r0 < NN; r0 += gridDim.x * 8) {
        float2 xv = *reinterpret_cast<const float2*>(&h[(size_t)r0 * F1 + lane * 2]);
        xs[wave][lane * 2]     = xv.x;
        xs[wave][lane * 2 + 1] = xv.y;
        int row = r0 + half;
        float acc = 0.f;
        #pragma unroll 16
        for (int k = 0; k < F1; ++k)
            acc = fmaf(xs[wave][half * F1 + k], Ws[k * F2 + j], acc);
        z[row * F2 + j] = acc;
        float pl = acc * a_l, pr = acc * a_r;
        #pragma unroll
        for (int mm = 1; mm < 32; mm <<= 1) {
            pl += __shfl_xor(pl, mm);
            pr += __shfl_xor(pr, mm);
        }
        if (j == 0) { el[row] = pl; er[row] = pr; }
    }
}

// ==================== CSR build (once per call, shared by both layers) =====

__global__ void zero_deg_kernel(int* __restrict__ deg)
{
    int i = blockIdx.x * blockDim.x + threadIdx.x;
    if (i < NN) deg[i] = 0;
}

__global__ void count_deg_kernel(const int* __restrict__ dst, int* __restrict__ deg)
{
    int e = blockIdx.x * blockDim.x + threadIdx.x;
    if (e < NE) atomicAdd(&deg[dst[e]], 1);
}

// block-level inclusive scan of deg -> scn, block totals -> bsum
__global__ __launch_bounds__(256) void scan1_kernel(
    const int* __restrict__ deg, int* __restrict__ scn, int* __restrict__ bsum)
{
    __shared__ int tmp[256];
    int i = blockIdx.x * 256 + threadIdx.x;
    int v = (i < NN) ? deg[i] : 0;
    tmp[threadIdx.x] = v;
    __syncthreads();
    for (int off = 1; off < 256; off <<= 1) {
        int t = (threadIdx.x >= off) ? tmp[threadIdx.x - off] : 0;
        __syncthreads();
        tmp[threadIdx.x] += t;
        __syncthreads();
    }
    if (i < NN) scn[i] = tmp[threadIdx.x];
    if (threadIdx.x == 255) bsum[blockIdx.x] = tmp[255];
}

// single block: exclusive scan of NB block sums in place
__global__ __launch_bounds__(256) void scan2_kernel(int* __restrict__ bsum)
{
    __shared__ int tmp[256];
    int v = (threadIdx.x < NB) ? bsum[threadIdx.x] : 0;
    tmp[threadIdx.x] = v;
    __syncthreads();
    for (int off = 1; off < 256; off <<= 1) {
        int t = (threadIdx.x >= off) ? tmp[threadIdx.x - off] : 0;
        __syncthreads();
        tmp[threadIdx.x] += t;
        __syncthreads();
    }
    if (threadIdx.x < NB) bsum[threadIdx.x] = tmp[threadIdx.x] - v; // exclusive
}

// row_start[i] = exclusive scan; fill_pos aliases scn (read own index then overwrite)
__global__ void scan3_kernel(const int* __restrict__ deg, int* __restrict__ scn_fillpos,
                             const int* __restrict__ bsum, int* __restrict__ row_start)
{
    int i = blockIdx.x * 256 + threadIdx.x;
    if (i < NN) {
        int ex = scn_fillpos[i] - deg[i] + bsum[blockIdx.x];
        row_start[i] = ex;
        scn_fillpos[i] = ex;
    }
    if (i == 0) row_start[NN] = NE;
}

__global__ void fill_kernel(const int* __restrict__ src, const int* __restrict__ dst,
                            int* __restrict__ fill_pos, int* __restrict__ srcs)
{
    int e = blockIdx.x * blockDim.x + threadIdx.x;
    if (e >= NE) return;
    int p = atomicAdd(&fill_pos[dst[e]], 1);
    srcs[p] = src[e];
}

// ==================== fused attention aggregation (gather, no atomics) =====
// One wave per dst node, F=64. Pass C processes 4 edges concurrently:
// lane = g*16 + c, g = edge slot (0..3), c = float4 feature chunk (0..15).
__global__ __launch_bounds__(256) void gat_agg64_kernel(
    const int* __restrict__ row_start, const int* __restrict__ srcs,
    const float* __restrict__ el, const float* __restrict__ er,
    const float* __restrict__ z, const float* __restrict__ b,
    float* __restrict__ out, float slope_out)
{
    int node = (blockIdx.x * 256 + threadIdx.x) >> 6;
    if (node >= NN) return;
    int lane = threadIdx.x & 63;
    int g = lane >> 4, c = lane & 15;
    int beg = row_start[node], end = row_start[node + 1];
    float erd = er[node];

    // pass A: segment max (lane-strided)
    int i0 = beg + lane;
    float v0 = -INFINITY;
    if (i0 < end) v0 = lrelu(el[srcs[i0]] + erd, 0.2f);
    float lm = v0;
    for (int i = i0 + 64; i < end; i += 64)
        lm = fmaxf(lm, lrelu(el[srcs[i]] + erd, 0.2f));
    #pragma unroll
    for (int mm = 1; mm < 64; mm <<= 1) lm = fmaxf(lm, __shfl_xor(lm, mm));

    // pass B: exp + segment sum; p for edge (beg+lane) stays in register
    float preg = 0.f, ls = 0.f;
    if (i0 < end) { preg = __expf(v0 - lm); ls = preg; }
    for (int i = i0 + 64; i < end; i += 64)
        ls += __expf(lrelu(el[srcs[i]] + erd, 0.2f) - lm);
    #pragma unroll
    for (int mm = 1; mm < 64; mm <<= 1) ls += __shfl_xor(ls, mm);
    float inv_s = (ls > 0.f) ? 1.0f / ls : 0.f;

    // pass C: weighted feature gather, 4 edges in flight, float4 per lane
    const float4* z4 = reinterpret_cast<const float4*>(z);
    float4 acc = {0.f, 0.f, 0.f, 0.f};
    for (int ib = beg; ib < end; ib += 4) {
        int i = ib + g;
        int j = i - beg;
        float pv = __shfl(preg, j & 63);   // unconditional: all lanes participate
        if (i < end) {
            int sn = srcs[i];
            if (j >= 64) pv = __expf(lrelu(el[sn] + erd, 0.2f) - lm); // rare tail
            float alpha = pv * inv_s;
            float4 zv = z4[(size_t)sn * 16 + c];
            acc.x = fmaf(alpha, zv.x, acc.x);
            acc.y = fmaf(alpha, zv.y, acc.y);
            acc.z = fmaf(alpha, zv.z, acc.z);
            acc.w = fmaf(alpha, zv.w, acc.w);
        }
    }
    #pragma unroll
    for (int mm = 16; mm < 64; mm <<= 1) {
        acc.x += __shfl_xor(acc.x, mm);
        acc.y += __shfl_xor(acc.y, mm);
        acc.z += __shfl_xor(acc.z, mm);
        acc.w += __shfl_xor(acc.w, mm);
    }
    if (g == 0) {
        float4 bb = reinterpret_cast<const float4*>(b)[c];
        float4 o;
        o.x = lrelu(acc.x + bb.x, slope_out);
        o.y = lrelu(acc.y + bb.y, slope_out);
        o.z = lrelu(acc.z + bb.z, slope_out);
        o.w = lrelu(acc.w + bb.w, slope_out);
        reinterpret_cast<float4*>(out)[(size_t)node * 16 + c] = o;
    }
}

// Half-wave per dst node, F=32. g = sub>>3 (edge slot), c = sub&7 (float4 chunk).
__global__ __launch_bounds__(256) void gat_agg32_kernel(
    const int* __restrict__ row_start, const int* __restrict__ srcs,
    const float* __restrict__ el, const float* __restrict__ er,
    const float* __restrict__ z, const float* __restrict__ b,
    float* __restrict__ out, float slope_out)
{
    int node = (blockIdx.x * 256 + threadIdx.x) >> 5;
    if (node >= NN) return;
    int sub = threadIdx.x & 31;
    int base = threadIdx.x & 32;       // absolute lane base of this half-wave
    int g = sub >> 3, c = sub & 7;
    int beg = row_start[node], end = row_start[node + 1];
    float erd = er[node];

    int i0 = beg + sub;
    float v0 = -INFINITY;
    if (i0 < end) v0 = lrelu(el[srcs[i0]] + erd, 0.2f);
    float lm = v0;
    for (int i = i0 + 32; i < end; i += 32)
        lm = fmaxf(lm, lrelu(el[srcs[i]] + erd, 0.2f));
    #pragma unroll
    for (int mm = 1; mm < 32; mm <<= 1) lm = fmaxf(lm, __shfl_xor(lm, mm));

    float preg = 0.f, ls = 0.f;
    if (i0 < end) { preg = __expf(v0 - lm); ls = preg; }
    for (int i = i0 + 32; i < end; i += 32)
        ls += __expf(lrelu(el[srcs[i]] + erd, 0.2f) - lm);
    #pragma unroll
    for (int mm = 1; mm < 32; mm <<= 1) ls += __shfl_xor(ls, mm);
    float inv_s = (ls > 0.f) ? 1.0f / ls : 0.f;

    const float4* z4 = reinterpret_cast<const float4*>(z);
    float4 acc = {0.f, 0.f, 0.f, 0.f};
    for (int ib = beg; ib < end; ib += 4) {
        int i = ib + g;
        int j = i - beg;
        float pv = __shfl(preg, base | (j & 31));
        if (i < end) {
            int sn = srcs[i];
            if (j >= 32) pv = __expf(lrelu(el[sn] + erd, 0.2f) - lm); // rare tail
            float alpha = pv * inv_s;
            float4 zv = z4[(size_t)sn * 8 + c];
            acc.x = fmaf(alpha, zv.x, acc.x);
            acc.y = fmaf(alpha, zv.y, acc.y);
            acc.z = fmaf(alpha, zv.z, acc.z);
            acc.w = fmaf(alpha, zv.w, acc.w);
        }
    }
    #pragma unroll
    for (int mm = 8; mm < 32; mm <<= 1) {
        acc.x += __shfl_xor(acc.x, mm);
        acc.y += __shfl_xor(acc.y, mm);
        acc.z += __shfl_xor(acc.z, mm);
        acc.w += __shfl_xor(acc.w, mm);
    }
    if (g == 0) {
        float4 bb = reinterpret_cast<const float4*>(b)[c];
        float4 o;
        o.x = lrelu(acc.x + bb.x, slope_out);
        o.y = lrelu(acc.y + bb.y, slope_out);
        o.z = lrelu(acc.z + bb.z, slope_out);
        o.w = lrelu(acc.w + bb.w, slope_out);
        reinterpret_cast<float4*>(out)[(size_t)node * 8 + c] = o;
    }
}

// ---- per-graph mean pool (graph_id sorted); one block per graph
__global__ __launch_bounds__(256) void pool_kernel(
    const float* __restrict__ h2, const int* __restrict__ gid, float* __restrict__ out)
{
    int g = blockIdx.x;
    int lo = 0, hi = NN;
    while (lo < hi) { int mid = (lo + hi) >> 1; if (gid[mid] < g) lo = mid + 1; else hi = mid; }
    int start = lo;
    hi = NN;
    while (lo < hi) { int mid = (lo + hi) >> 1; if (gid[mid] < g + 1) lo = mid + 1; else hi = mid; }
    int end = lo;

    int f = threadIdx.x & 31, r = threadIdx.x >> 5;
    float acc = 0.f;
    for (int n = start + r; n < end; n += 8) acc += h2[(size_t)n * F2 + f];
    __shared__ float red[256];
    red[threadIdx.x] = acc;
    __syncthreads();
    for (int st = 128; st >= 32; st >>= 1) {
        if (threadIdx.x < st) red[threadIdx.x] += red[threadIdx.x + st];
        __syncthreads();
    }
    if (threadIdx.x < 32) {
        float cnt = (float)(end - start);
        out[g * F2 + threadIdx.x] = red[threadIdx.x] / fmaxf(cnt, 1.0f);
    }
}

extern "C" void kernel_launch(void* const* d_in, const int* in_sizes, int n_in,
                              void* d_out, int out_size, void* d_ws, size_t ws_size,
                              hipStream_t stream)
{
    const float* x   = (const float*)d_in[0];
    const int*   src = (const int*)d_in[1];
    const int*   dst = (const int*)d_in[2];
    const int*   gid = (const int*)d_in[3];
    const float* W1  = (const float*)d_in[4];
    const float* al1 = (const float*)d_in[5];
    const float* ar1 = (const float*)d_in[6];
    const float* b1  = (const float*)d_in[7];
    const float* W2  = (const float*)d_in[8];
    const float* al2 = (const float*)d_in[9];
    const float* ar2 = (const float*)d_in[10];
    const float* b2  = (const float*)d_in[11];
    float* out = (float*)d_out;

    float* ws   = (float*)d_ws;
    float* z1   = ws;                            // NN*64
    float* h1   = z1 + (size_t)NN * F1;          // NN*64
    float* z2   = h1 + (size_t)NN * F1;          // NN*32
    float* h2   = z2 + (size_t)NN * F2;          // NN*32
    float* el   = h2 + (size_t)NN * F2;          // NN
    float* er   = el + NN;                       // NN
    int* deg       = (int*)(er + NN);            // NN
    int* scn_fill  = deg + NN;                   // NN (scan buf, then fill_pos)
    int* bsum      = scn_fill + NN;              // 256
    int* row_start = bsum + 256;                 // NN+1
    int* srcs      = row_start + NN + 1;         // NE

    // ---- CSR build (dst-sorted adjacency), shared by both layers
    zero_deg_kernel<<<NB, 256, 0, stream>>>(deg);
    count_deg_kernel<<<(NE + 255) / 256, 256, 0, stream>>>(dst, deg);
    scan1_kernel<<<NB, 256, 0, stream>>>(deg, scn_fill, bsum);
    scan2_kernel<<<1, 256, 0, stream>>>(bsum);
    scan3_kernel<<<NB, 256, 0, stream>>>(deg, scn_fill, bsum, row_start);
    fill_kernel<<<(NE + 255) / 256, 256, 0, stream>>>(src, dst, scn_fill, srcs);

    // ---- layer 1
    gemm1_kernel<<<1024, 256, 0, stream>>>(x, W1, al1, ar1, z1, el, er);
    gat_agg64_kernel<<<(NN * 64 + 255) / 256, 256, 0, stream>>>(
        row_start, srcs, el, er, z1, b1, h1, 0.01f);

    // ---- layer 2
    gemm2_kernel<<<1024, 256, 0, stream>>>(h1, W2, al2, ar2, z2, el, er);
    gat_agg32_kernel<<<(NN * 32 + 255) / 256, 256, 0, stream>>>(
        row_start, srcs, el, er, z2, b2, h2, 0.01f);

    // ---- per-graph mean pool
    pool_kernel<<<NG, 256, 0, stream>>>(h2, gid, out);
}

// Round 5
// 283.379 us; speedup vs baseline: 2.2549x; 1.2357x over previous
//
#include <hip/hip_runtime.h>
#include <math.h>

#define NN 50000
#define NE 800000
#define NG 50
#define F0 128
#define F1 64
#define F2 32
#define NPB 256                  // nodes per bucket (bucket = dst >> 8)
#define NBK 196                  // ceil(NN/NPB)
#define CHUNK 4096
#define NC 196                   // ceil(NE/CHUNK)

__device__ __forceinline__ float lrelu(float v, float slope) {
    return v > 0.0f ? v : v * slope;
}

// ---- GEMM1: z = x@W (NN x 128 @ 128 x 64); el = z@al, er = z@ar fused
__global__ __launch_bounds__(256) void gemm1_kernel(
    const float* __restrict__ x, const float* __restrict__ W,
    const float* __restrict__ al, const float* __restrict__ ar,
    float* __restrict__ z, float* __restrict__ el, float* __restrict__ er)
{
    __shared__ float Ws[F0 * F1];
    __shared__ float xs[4][F0];
    int tid = threadIdx.x;
    for (int i = tid; i < F0 * F1; i += 256) Ws[i] = W[i];
    __syncthreads();
    int wave = tid >> 6, lane = tid & 63;
    float a_l = al[lane], a_r = ar[lane];
    for (int row = blockIdx.x * 4 + wave; row < NN; row += gridDim.x * 4) {
        float2 xv = *reinterpret_cast<const float2*>(&x[row * F0 + lane * 2]);
        xs[wave][lane * 2]     = xv.x;
        xs[wave][lane * 2 + 1] = xv.y;
        float acc = 0.f;
        #pragma unroll 16
        for (int k = 0; k < F0; ++k)
            acc = fmaf(xs[wave][k], Ws[k * F1 + lane], acc);
        z[row * F1 + lane] = acc;
        float pl = acc * a_l, pr = acc * a_r;
        #pragma unroll
        for (int mm = 1; mm < 64; mm <<= 1) {
            pl += __shfl_xor(pl, mm);
            pr += __shfl_xor(pr, mm);
        }
        if (lane == 0) { el[row] = pl; er[row] = pr; }
    }
}

// ---- GEMM2: z = h@W (NN x 64 @ 64 x 32); half-wave per row
__global__ __launch_bounds__(256) void gemm2_kernel(
    const float* __restrict__ h, const float* __restrict__ W,
    const float* __restrict__ al, const float* __restrict__ ar,
    float* __restrict__ z, float* __restrict__ el, float* __restrict__ er)
{
    __shared__ float Ws[F1 * F2];
    __shared__ float xs[4][2 * F1];
    int tid = threadIdx.x;
    for (int i = tid; i < F1 * F2; i += 256) Ws[i] = W[i];
    __syncthreads();
    int wave = tid >> 6, lane = tid & 63;
    int half = lane >> 5, j = lane & 31;
    float a_l = al[j], a_r = ar[j];
    for (int r0 = (blockIdx.x * 4 + wave) * 2; r0 < NN; r0 += gridDim.x * 8) {
        float2 xv = *reinterpret_cast<const float2*>(&h[(size_t)r0 * F1 + lane * 2]);
        xs[wave][lane * 2]     = xv.x;
        xs[wave][lane * 2 + 1] = xv.y;
        int row = r0 + half;
        float acc = 0.f;
        #pragma unroll 16
        for (int k = 0; k < F1; ++k)
            acc = fmaf(xs[wave][half * F1 + k], Ws[k * F2 + j], acc);
        z[row * F2 + j] = acc;
        float pl = acc * a_l, pr = acc * a_r;
        #pragma unroll
        for (int mm = 1; mm < 32; mm <<= 1) {
            pl += __shfl_xor(pl, mm);
            pr += __shfl_xor(pr, mm);
        }
        if (j == 0) { el[row] = pl; er[row] = pr; }
    }
}

// ========== CSR build via 2-level counting sort (dense writes only) ==========

// per-chunk histogram over dst buckets -> hist[bucket][chunk]
__global__ __launch_bounds__(256) void p1_hist_kernel(
    const int* __restrict__ dst, int* __restrict__ hist)
{
    __shared__ int h[NBK];
    int c = blockIdx.x;
    if (threadIdx.x < NBK) h[threadIdx.x] = 0;
    __syncthreads();
    int e0 = c * CHUNK;
    int e1 = (e0 + CHUNK < NE) ? e0 + CHUNK : NE;
    for (int e = e0 + threadIdx.x; e < e1; e += 256)
        atomicAdd(&h[dst[e] >> 8], 1);
    __syncthreads();
    if (threadIdx.x < NBK) hist[threadIdx.x * NC + c] = h[threadIdx.x];
}

// per-bucket exclusive scan over chunks (in place); bucket totals out
__global__ __launch_bounds__(256) void p2a_scan_kernel(
    int* __restrict__ hist, int* __restrict__ btot)
{
    __shared__ int t[256];
    int b = blockIdx.x;
    int v = (threadIdx.x < NC) ? hist[b * NC + threadIdx.x] : 0;
    t[threadIdx.x] = v;
    __syncthreads();
    for (int off = 1; off < 256; off <<= 1) {
        int u = (threadIdx.x >= off) ? t[threadIdx.x - off] : 0;
        __syncthreads();
        t[threadIdx.x] += u;
        __syncthreads();
    }
    if (threadIdx.x < NC) hist[b * NC + threadIdx.x] = t[threadIdx.x] - v; // exclusive
    if (threadIdx.x == 255) btot[b] = t[255];
}

// single block: exclusive scan of bucket totals -> bstart
__global__ __launch_bounds__(256) void p2b_scan_kernel(
    const int* __restrict__ btot, int* __restrict__ bstart, int* __restrict__ row_start)
{
    __shared__ int t[256];
    int v = (threadIdx.x < NBK) ? btot[threadIdx.x] : 0;
    t[threadIdx.x] = v;
    __syncthreads();
    for (int off = 1; off < 256; off <<= 1) {
        int u = (threadIdx.x >= off) ? t[threadIdx.x - off] : 0;
        __syncthreads();
        t[threadIdx.x] += u;
        __syncthreads();
    }
    if (threadIdx.x < NBK) bstart[threadIdx.x] = t[threadIdx.x] - v;
    if (threadIdx.x == NBK) bstart[NBK] = NE;
    if (threadIdx.x == 0) row_start[NN] = NE;
}

// partition edges into bucket-contiguous (src,dst) pairs
__global__ __launch_bounds__(256) void p3_part_kernel(
    const int* __restrict__ src, const int* __restrict__ dst,
    const int* __restrict__ hist, const int* __restrict__ bstart,
    int2* __restrict__ part)
{
    __shared__ int base[NBK];
    __shared__ int cnt[NBK];
    int c = blockIdx.x;
    if (threadIdx.x < NBK) {
        base[threadIdx.x] = hist[threadIdx.x * NC + c] + bstart[threadIdx.x];
        cnt[threadIdx.x] = 0;
    }
    __syncthreads();
    int e0 = c * CHUNK;
    int e1 = (e0 + CHUNK < NE) ? e0 + CHUNK : NE;
    for (int e = e0 + threadIdx.x; e < e1; e += 256) {
        int s = src[e], d = dst[e];
        int b = d >> 8;
        int r = atomicAdd(&cnt[b], 1);
        part[base[b] + r] = make_int2(s, d);
    }
}

// per-bucket: degree hist -> scan -> row_start + ranked srcs (dense region)
__global__ __launch_bounds__(256) void p4_fill_kernel(
    const int2* __restrict__ part, const int* __restrict__ bstart,
    int* __restrict__ row_start, int* __restrict__ srcs)
{
    __shared__ int deg[NPB];
    __shared__ int off[NPB];
    __shared__ int cnt[NPB];
    int b = blockIdx.x;
    int lo = bstart[b], hi = bstart[b + 1];
    deg[threadIdx.x] = 0;
    cnt[threadIdx.x] = 0;
    __syncthreads();
    for (int i = lo + threadIdx.x; i < hi; i += 256)
        atomicAdd(&deg[part[i].y & (NPB - 1)], 1);
    __syncthreads();
    int v = deg[threadIdx.x];
    off[threadIdx.x] = v;
    __syncthreads();
    for (int o = 1; o < 256; o <<= 1) {
        int u = (threadIdx.x >= o) ? off[threadIdx.x - o] : 0;
        __syncthreads();
        off[threadIdx.x] += u;
        __syncthreads();
    }
    int ex = off[threadIdx.x] - v;
    __syncthreads();
    off[threadIdx.x] = ex;
    __syncthreads();
    int node = b * NPB + threadIdx.x;
    if (node < NN) row_start[node] = lo + ex;
    for (int i = lo + threadIdx.x; i < hi; i += 256) {
        int2 e = part[i];
        int n = e.y & (NPB - 1);
        int r = atomicAdd(&cnt[n], 1);
        srcs[lo + off[n] + r] = e.x;
    }
}

// ==================== fused attention aggregation (gather, no atomics) =====
// One wave per dst node, F=64. Pass C processes 4 edges concurrently:
// lane = g*16 + c, g = edge slot (0..3), c = float4 feature chunk (0..15).
__global__ __launch_bounds__(256) void gat_agg64_kernel(
    const int* __restrict__ row_start, const int* __restrict__ srcs,
    const float* __restrict__ el, const float* __restrict__ er,
    const float* __restrict__ z, const float* __restrict__ b,
    float* __restrict__ out, float slope_out)
{
    int node = (blockIdx.x * 256 + threadIdx.x) >> 6;
    if (node >= NN) return;
    int lane = threadIdx.x & 63;
    int g = lane >> 4, c = lane & 15;
    int beg = row_start[node], end = row_start[node + 1];
    float erd = er[node];

    // pass A: segment max (lane-strided)
    int i0 = beg + lane;
    float v0 = -INFINITY;
    if (i0 < end) v0 = lrelu(el[srcs[i0]] + erd, 0.2f);
    float lm = v0;
    for (int i = i0 + 64; i < end; i += 64)
        lm = fmaxf(lm, lrelu(el[srcs[i]] + erd, 0.2f));
    #pragma unroll
    for (int mm = 1; mm < 64; mm <<= 1) lm = fmaxf(lm, __shfl_xor(lm, mm));

    // pass B: exp + segment sum; p for edge (beg+lane) stays in register
    float preg = 0.f, ls = 0.f;
    if (i0 < end) { preg = __expf(v0 - lm); ls = preg; }
    for (int i = i0 + 64; i < end; i += 64)
        ls += __expf(lrelu(el[srcs[i]] + erd, 0.2f) - lm);
    #pragma unroll
    for (int mm = 1; mm < 64; mm <<= 1) ls += __shfl_xor(ls, mm);
    float inv_s = (ls > 0.f) ? 1.0f / ls : 0.f;

    // pass C: weighted feature gather, 4 edges in flight, float4 per lane
    const float4* z4 = reinterpret_cast<const float4*>(z);
    float4 acc = {0.f, 0.f, 0.f, 0.f};
    for (int ib = beg; ib < end; ib += 4) {
        int i = ib + g;
        int j = i - beg;
        float pv = __shfl(preg, j & 63);   // unconditional: all lanes participate
        if (i < end) {
            int sn = srcs[i];
            if (j >= 64) pv = __expf(lrelu(el[sn] + erd, 0.2f) - lm); // rare tail
            float alpha = pv * inv_s;
            float4 zv = z4[(size_t)sn * 16 + c];
            acc.x = fmaf(alpha, zv.x, acc.x);
            acc.y = fmaf(alpha, zv.y, acc.y);
            acc.z = fmaf(alpha, zv.z, acc.z);
            acc.w = fmaf(alpha, zv.w, acc.w);
        }
    }
    #pragma unroll
    for (int mm = 16; mm < 64; mm <<= 1) {
        acc.x += __shfl_xor(acc.x, mm);
        acc.y += __shfl_xor(acc.y, mm);
        acc.z += __shfl_xor(acc.z, mm);
        acc.w += __shfl_xor(acc.w, mm);
    }
    if (g == 0) {
        float4 bb = reinterpret_cast<const float4*>(b)[c];
        float4 o;
        o.x = lrelu(acc.x + bb.x, slope_out);
        o.y = lrelu(acc.y + bb.y, slope_out);
        o.z = lrelu(acc.z + bb.z, slope_out);
        o.w = lrelu(acc.w + bb.w, slope_out);
        reinterpret_cast<float4*>(out)[(size_t)node * 16 + c] = o;
    }
}

// Half-wave per dst node, F=32. g = sub>>3 (edge slot), c = sub&7 (float4 chunk).
__global__ __launch_bounds__(256) void gat_agg32_kernel(
    const int* __restrict__ row_start, const int* __restrict__ srcs,
    const float* __restrict__ el, const float* __restrict__ er,
    const float* __restrict__ z, const float* __restrict__ b,
    float* __restrict__ out, float slope_out)
{
    int node = (blockIdx.x * 256 + threadIdx.x) >> 5;
    if (node >= NN) return;
    int sub = threadIdx.x & 31;
    int base = threadIdx.x & 32;       // absolute lane base of this half-wave
    int g = sub >> 3, c = sub & 7;
    int beg = row_start[node], end = row_start[node + 1];
    float erd = er[node];

    int i0 = beg + sub;
    float v0 = -INFINITY;
    if (i0 < end) v0 = lrelu(el[srcs[i0]] + erd, 0.2f);
    float lm = v0;
    for (int i = i0 + 32; i < end; i += 32)
        lm = fmaxf(lm, lrelu(el[srcs[i]] + erd, 0.2f));
    #pragma unroll
    for (int mm = 1; mm < 32; mm <<= 1) lm = fmaxf(lm, __shfl_xor(lm, mm));

    float preg = 0.f, ls = 0.f;
    if (i0 < end) { preg = __expf(v0 - lm); ls = preg; }
    for (int i = i0 + 32; i < end; i += 32)
        ls += __expf(lrelu(el[srcs[i]] + erd, 0.2f) - lm);
    #pragma unroll
    for (int mm = 1; mm < 32; mm <<= 1) ls += __shfl_xor(ls, mm);
    float inv_s = (ls > 0.f) ? 1.0f / ls : 0.f;

    const float4* z4 = reinterpret_cast<const float4*>(z);
    float4 acc = {0.f, 0.f, 0.f, 0.f};
    for (int ib = beg; ib < end; ib += 4) {
        int i = ib + g;
        int j = i - beg;
        float pv = __shfl(preg, base | (j & 31));
        if (i < end) {
            int sn = srcs[i];
            if (j >= 32) pv = __expf(lrelu(el[sn] + erd, 0.2f) - lm); // rare tail
            float alpha = pv * inv_s;
            float4 zv = z4[(size_t)sn * 8 + c];
            acc.x = fmaf(alpha, zv.x, acc.x);
            acc.y = fmaf(alpha, zv.y, acc.y);
            acc.z = fmaf(alpha, zv.z, acc.z);
            acc.w = fmaf(alpha, zv.w, acc.w);
        }
    }
    #pragma unroll
    for (int mm = 8; mm < 32; mm <<= 1) {
        acc.x += __shfl_xor(acc.x, mm);
        acc.y += __shfl_xor(acc.y, mm);
        acc.z += __shfl_xor(acc.z, mm);
        acc.w += __shfl_xor(acc.w, mm);
    }
    if (g == 0) {
        float4 bb = reinterpret_cast<const float4*>(b)[c];
        float4 o;
        o.x = lrelu(acc.x + bb.x, slope_out);
        o.y = lrelu(acc.y + bb.y, slope_out);
        o.z = lrelu(acc.z + bb.z, slope_out);
        o.w = lrelu(acc.w + bb.w, slope_out);
        reinterpret_cast<float4*>(out)[(size_t)node * 8 + c] = o;
    }
}

// ---- per-graph mean pool (graph_id sorted); one block per graph
__global__ __launch_bounds__(256) void pool_kernel(
    const float* __restrict__ h2, const int* __restrict__ gid, float* __restrict__ out)
{
    int g = blockIdx.x;
    int lo = 0, hi = NN;
    while (lo < hi) { int mid = (lo + hi) >> 1; if (gid[mid] < g) lo = mid + 1; else hi = mid; }
    int start = lo;
    hi = NN;
    while (lo < hi) { int mid = (lo + hi) >> 1; if (gid[mid] < g + 1) lo = mid + 1; else hi = mid; }
    int end = lo;

    int f = threadIdx.x & 31, r = threadIdx.x >> 5;
    float acc = 0.f;
    for (int n = start + r; n < end; n += 8) acc += h2[(size_t)n * F2 + f];
    __shared__ float red[256];
    red[threadIdx.x] = acc;
    __syncthreads();
    for (int st = 128; st >= 32; st >>= 1) {
        if (threadIdx.x < st) red[threadIdx.x] += red[threadIdx.x + st];
        __syncthreads();
    }
    if (threadIdx.x < 32) {
        float cnt = (float)(end - start);
        out[g * F2 + threadIdx.x] = red[threadIdx.x] / fmaxf(cnt, 1.0f);
    }
}

extern "C" void kernel_launch(void* const* d_in, const int* in_sizes, int n_in,
                              void* d_out, int out_size, void* d_ws, size_t ws_size,
                              hipStream_t stream)
{
    const float* x   = (const float*)d_in[0];
    const int*   src = (const int*)d_in[1];
    const int*   dst = (const int*)d_in[2];
    const int*   gid = (const int*)d_in[3];
    const float* W1  = (const float*)d_in[4];
    const float* al1 = (const float*)d_in[5];
    const float* ar1 = (const float*)d_in[6];
    const float* b1  = (const float*)d_in[7];
    const float* W2  = (const float*)d_in[8];
    const float* al2 = (const float*)d_in[9];
    const float* ar2 = (const float*)d_in[10];
    const float* b2  = (const float*)d_in[11];
    float* out = (float*)d_out;

    float* ws   = (float*)d_ws;
    float* z1   = ws;                            // NN*64 floats
    float* h1   = z1 + (size_t)NN * F1;          // NN*64
    float* z2   = h1 + (size_t)NN * F1;          // NN*32
    float* h2   = z2 + (size_t)NN * F2;          // NN*32
    float* el   = h2 + (size_t)NN * F2;          // NN
    float* er   = el + NN;                       // NN
    int* row_start = (int*)(er + NN);            // NN+1
    int* srcs      = row_start + NN + 1;         // NE
    int* hist      = srcs + NE;                  // NBK*NC
    int* btot      = hist + NBK * NC;            // NBK
    int* bstart    = btot + NBK;                 // NBK+1
    // part[] aliases z1 (dead until gemm1 writes z1, which runs after p4)
    int2* part = reinterpret_cast<int2*>(z1);    // NE int2 = 6.4MB <= 12.8MB

    // ---- CSR build (counting sort; all global writes dense)
    p1_hist_kernel<<<NC, 256, 0, stream>>>(dst, hist);
    p2a_scan_kernel<<<NBK, 256, 0, stream>>>(hist, btot);
    p2b_scan_kernel<<<1, 256, 0, stream>>>(btot, bstart, row_start);
    p3_part_kernel<<<NC, 256, 0, stream>>>(src, dst, hist, bstart, part);
    p4_fill_kernel<<<NBK, 256, 0, stream>>>(part, bstart, row_start, srcs);

    // ---- layer 1
    gemm1_kernel<<<1024, 256, 0, stream>>>(x, W1, al1, ar1, z1, el, er);
    gat_agg64_kernel<<<(NN * 64 + 255) / 256, 256, 0, stream>>>(
        row_start, srcs, el, er, z1, b1, h1, 0.01f);

    // ---- layer 2
    gemm2_kernel<<<1024, 256, 0, stream>>>(h1, W2, al2, ar2, z2, el, er);
    gat_agg32_kernel<<<(NN * 32 + 255) / 256, 256, 0, stream>>>(
        row_start, srcs, el, er, z2, b2, h2, 0.01f);

    // ---- per-graph mean pool
    pool_kernel<<<NG, 256, 0, stream>>>(h2, gid, out);
}